// Round 18
// baseline (24.560 us; speedup 1.0000x reference)
//
#include <hip/hip_runtime.h>

// FFT convolution via N = 2^18 = 256 x 1024 Cooley-Tukey, 3 dispatches
// (minimum for four-step: col-pass | row-local middle | col-pass).
//   n = 1024*n1 + n2 (nonzero n1<128), k = k1 + 256*k2.
// ka: distributed 256-pt column FFT over n1 (+ W_N^{-n2 k1}) -> A1[seq][k1][n2]
//     192 blocks x 256 thr (16 cols x 16 slots): float audio loads keep 64B
//     granule (R15 lesson: 128-thr ka drops to 32B and regresses).
// kb: 512 blocks x 256 (2 blocks/CU): fwd 1024-FFT rir row (regs) + fwd z row +
//     pointwise*1/N + inverse FFT + W_N^{+n2 k1} -> D[z][k1][n2].  (R14 exact;
//     R17 pairing regressed: barriers not binding.)
// kc: 256 blocks x 128 thr (8 cols x 16 slots): float2 loads keep 64B granule,
//     and 256 blocks = 1 block/CU (was 128 = half the chip idle).
// No cross-block sync (R6/R9/R10: every variant costs more than a dispatch).

#define NTOT 262144
#define TLEN 131072
#define PI2_N    2.3968449808418217e-5f   /* 2*pi / 262144 */
#define PI2_1024 6.1359231515425649e-3f   /* 2*pi / 1024   */
#define PI2_256  2.4543692606170260e-2f   /* 2*pi / 256    */
#define LB(i) ((i) + ((i) >> 3))          /* LDS pad for row-FFT buffers */
#define CIDX(R, c) ((R) * 9 + ((R) >> 4) + (c))   /* kc col-exchange pad, c in [0,8) */

__device__ __forceinline__ float2 cadd(float2 a, float2 b) { return make_float2(a.x + b.x, a.y + b.y); }
__device__ __forceinline__ float2 csub(float2 a, float2 b) { return make_float2(a.x - b.x, a.y - b.y); }
__device__ __forceinline__ float2 cmul(float2 a, float2 b) {
    return make_float2(a.x * b.x - a.y * b.y, a.x * b.y + a.y * b.x);
}
__device__ __forceinline__ float2 cmulc(float2 a, float2 b) {   // a * conj(b)
    return make_float2(a.x * b.x + a.y * b.y, a.y * b.x - a.x * b.y);
}
__device__ __forceinline__ float2 cexp_(float ang) {
    float s, c;
    __sincosf(ang, &s, &c);
    return make_float2(c, s);
}

// cos/sin(2*pi*k/16)
constexpr float CW16[16] = { 1.f, 0.92387953f, 0.70710678f, 0.38268343f, 0.f, -0.38268343f,
                             -0.70710678f, -0.92387953f, -1.f, -0.92387953f, -0.70710678f,
                             -0.38268343f, 0.f, 0.38268343f, 0.70710678f, 0.92387953f };
constexpr float SW16[16] = { 0.f, 0.38268343f, 0.70710678f, 0.92387953f, 1.f, 0.92387953f,
                             0.70710678f, 0.38268343f, 0.f, -0.38268343f, -0.70710678f,
                             -0.92387953f, -1.f, -0.92387953f, -0.70710678f, -0.38268343f };

template<int SIGN>
__device__ __forceinline__ void dft4(float2 x[4]) {
    float2 s0 = cadd(x[0], x[2]), d0 = csub(x[0], x[2]);
    float2 s1 = cadd(x[1], x[3]), d1 = csub(x[1], x[3]);
    float2 jd1 = (SIGN > 0) ? make_float2(-d1.y, d1.x) : make_float2(d1.y, -d1.x);
    x[0] = cadd(s0, s1);
    x[1] = cadd(d0, jd1);
    x[2] = csub(s0, s1);
    x[3] = csub(d0, jd1);
}

// Natural-order in-register 16-pt DFT (4x4). HZ: x[8..15] structurally zero (never read).
template<int SIGN, bool HZ>
__device__ __forceinline__ void dft16(float2 x[16]) {
    float2 A[4][4];                       // A[m0][j]
#pragma unroll
    for (int m0 = 0; m0 < 4; ++m0) {
        float2 g[4];
        if (HZ) {                         // dft4 of [a, b, 0, 0] over m1
            float2 a = x[m0], b = x[m0 + 4];
            float2 jb = (SIGN > 0) ? make_float2(-b.y, b.x) : make_float2(b.y, -b.x);
            g[0] = cadd(a, b);
            g[1] = cadd(a, jb);
            g[2] = csub(a, b);
            g[3] = csub(a, jb);
        } else {
            g[0] = x[m0]; g[1] = x[m0 + 4]; g[2] = x[m0 + 8]; g[3] = x[m0 + 12];
            dft4<SIGN>(g);
        }
#pragma unroll
        for (int j = 0; j < 4; ++j) {     // W16^{m0*j}, compile-time
            int k = (m0 * j) & 15;
            float2 w = make_float2(CW16[k], (SIGN < 0) ? -SW16[k] : SW16[k]);
            A[m0][j] = (m0 && j) ? cmul(g[j], w) : g[j];
        }
    }
#pragma unroll
    for (int j = 0; j < 4; ++j) {
        float2 g[4];
#pragma unroll
        for (int m0 = 0; m0 < 4; ++m0) g[m0] = A[m0][j];
        dft4<SIGN>(g);
#pragma unroll
        for (int l = 0; l < 4; ++l) x[j + 4 * l] = g[l];   // X[j+4l] natural
    }
}

template<int SIGN>
__device__ __forceinline__ void twtab4(float2 x[4], int base, const float2* __restrict__ tab) {
#pragma unroll
    for (int i = 1; i < 4; ++i) {
        float2 w = tab[base * i];          // base*i < 1024 at all call sites
        x[i] = (SIGN < 0) ? cmul(x[i], w) : cmulc(x[i], w);
    }
}

// 1024-pt radix-4 Stockham FFT, t in [0,256), x[i] = d[t+256i] natural in/out.
// 5 dft4 stages, 4 barriers, alternating L0/L1. Back-to-back calls WAR-safe.
template<int SIGN>
__device__ void fft1024(float2 x[4], int t, float2* L0, float2* L1,
                        const float2* __restrict__ tab) {
    dft4<SIGN>(x);
    twtab4<SIGN>(x, t, tab);
#pragma unroll
    for (int i = 0; i < 4; ++i) L0[LB(4 * t + i)] = x[i];
    __syncthreads();
    {
        int q = t & 3, p = t >> 2;
#pragma unroll
        for (int i = 0; i < 4; ++i) x[i] = L0[LB(q + 4 * p + 256 * i)];
        dft4<SIGN>(x);
        twtab4<SIGN>(x, 4 * p, tab);
#pragma unroll
        for (int i = 0; i < 4; ++i) L1[LB(q + 16 * p + 4 * i)] = x[i];
    }
    __syncthreads();
    {
        int q = t & 15, p = t >> 4;
#pragma unroll
        for (int i = 0; i < 4; ++i) x[i] = L1[LB(q + 16 * p + 256 * i)];
        dft4<SIGN>(x);
        twtab4<SIGN>(x, 16 * p, tab);
#pragma unroll
        for (int i = 0; i < 4; ++i) L0[LB(q + 64 * p + 16 * i)] = x[i];
    }
    __syncthreads();
    {
        int q = t & 63, p = t >> 6;
#pragma unroll
        for (int i = 0; i < 4; ++i) x[i] = L0[LB(q + 64 * p + 256 * i)];
        dft4<SIGN>(x);
        twtab4<SIGN>(x, 64 * p, tab);
#pragma unroll
        for (int i = 0; i < 4; ++i) L1[LB(q + 256 * p + 64 * i)] = x[i];
    }
    __syncthreads();
#pragma unroll
    for (int i = 0; i < 4; ++i) x[i] = L1[LB(t + 256 * i)];
    dft4<SIGN>(x);
}

// ka: 192 blocks x 256. 16 columns/block, 16 thr/column (c = tid&15 lane-consecutive).
__global__ void __launch_bounds__(256) ka(const float* __restrict__ audio,
                                          const float* __restrict__ rir,
                                          float2* __restrict__ A1,
                                          float2* __restrict__ tab) {
    __shared__ float2 lds[256 * 17];      // [a*16+u][c] padded row stride 17
    const int bid = blockIdx.x;
    const int tid = threadIdx.x;
    const int c = tid & 15;
    const int t = tid >> 4;               // 0..15

    if (bid < 4)                          // fill W1024 table for kb
        tab[bid * 256 + tid] = cexp_(-PI2_1024 * (float)(bid * 256 + tid));

    const int seq = bid >> 6;
    const int n2 = ((bid & 63) << 4) + c;

    float2 g[16];
    if (seq < 2) {
        const float* c0 = audio + (size_t)(2 * seq) * TLEN;
        const float* c1 = c0 + TLEN;
#pragma unroll
        for (int v = 0; v < 8; ++v) {     // n1 = t+16v < 128 nonzero half
            int n = ((t + 16 * v) << 10) + n2;
            g[v] = make_float2(c0[n], c1[n]);
        }
    } else {
#pragma unroll
        for (int v = 0; v < 8; ++v) {
            int n = ((t + 16 * v) << 10) + n2;
            g[v] = make_float2(rir[TLEN - 1 - n], 0.f);
        }
    }

    dft16<-1, true>(g);                   // bins a = reg index (natural)
    {                                     // W256^{-t*a}: chain from W256^{-t}
        float2 wa = cexp_(-PI2_256 * (float)t);
        float2 w = wa;
        g[1] = cmul(g[1], w);
#pragma unroll
        for (int r = 2; r < 16; ++r) { w = cmul(w, wa); g[r] = cmul(g[r], w); }
    }
#pragma unroll
    for (int r = 0; r < 16; ++r) lds[(r * 16 + t) * 17 + c] = g[r];
    __syncthreads();
#pragma unroll
    for (int u = 0; u < 16; ++u) g[u] = lds[(t * 16 + u) * 17 + c];  // a = t, sender u

    dft16<-1, false>(g);                  // over u -> bins b = reg index; k1 = t + 16b

    // W_N^{-n2*k1}, k1 = t+16r: base W_N^{-n2 t}, step W_N^{-16 n2}
    float2 w  = cexp_(-PI2_N * (float)(n2 * t));
    float2 ws = cexp_(-PI2_N * (float)(16 * n2));
    float2* dst = A1 + ((size_t)seq << 18) + n2;
#pragma unroll
    for (int r = 0; r < 16; ++r) {
        int k1 = t + 16 * r;
        dst[(size_t)k1 << 10] = cmul(g[r], w);
        w = cmul(w, ws);
    }
}

// kb: 512 blocks x 256. z = bid>>8, k1 = bid&255. Row-local middle (R14 exact):
// fwd FFT(rir row) -> 8 VGPRs; fwd FFT(z row); pointwise*1/N; inv FFT; twiddle -> D.
__global__ void __launch_bounds__(256) kb(const float2* __restrict__ A1,
                                          float2* __restrict__ D,
                                          const float2* __restrict__ tab) {
    __shared__ float2 L0[1152], L1[1152];
    const int t = threadIdx.x;
    const int k1 = blockIdx.x & 255;

    const float2* sz = A1 + ((size_t)blockIdx.x << 10);          // z row = z*256+k1 = bid
    const float2* sr = A1 + ((size_t)(512 + k1) << 10);          // rir row
    float2 x[4], r4[4];
#pragma unroll
    for (int i = 0; i < 4; ++i) x[i] = sz[t + 256 * i];          // issue early: both
#pragma unroll
    for (int i = 0; i < 4; ++i) r4[i] = sr[t + 256 * i];         // rows in flight

    fft1024<-1>(r4, t, L0, L1, tab);     // rir spectrum (z loads hide under this)
    fft1024<-1>(x, t, L0, L1, tab);      // z spectrum

    const float invN = 3.814697265625e-6f;   // 1/262144
#pragma unroll
    for (int i = 0; i < 4; ++i) {
        float2 y = cmul(x[i], r4[i]);
        x[i] = make_float2(y.x * invN, y.y * invN);
    }

    fft1024<1>(x, t, L0, L1, tab);

    // W_N^{+n2 k1}, n2 = t+256i: w = e^{+i th(t k1)}, step = conj(tab[k1])
    float2 w  = cexp_(PI2_N * (float)(t * k1));
    float2 st = make_float2(tab[k1].x, -tab[k1].y);
    float2* d = D + ((size_t)blockIdx.x << 10) + t;
#pragma unroll
    for (int i = 0; i < 4; ++i) {
        d[256 * i] = cmul(x[i], w);
        w = cmul(w, st);
    }
}

// kc: 256 blocks x 128. 8 columns/block, 16 thr/column (c = tid&7, t = tid>>3).
// float2 loads keep 64B/segment granule; 1 block/CU (all CUs busy).
__global__ void __launch_bounds__(128) kc(const float2* __restrict__ D,
                                          float* __restrict__ out, int Lout) {
    __shared__ float2 lds[2320];          // CIDX(255,7) = 2317
    const int bid = blockIdx.x;
    const int tid = threadIdx.x;
    const int c = tid & 7;
    const int t = tid >> 3;               // 0..15
    const int z = bid >> 7;
    const int n2 = ((bid & 127) << 3) + c;

    const float2* src = D + ((size_t)z << 18) + n2;
    float2 g[16];
#pragma unroll
    for (int v = 0; v < 16; ++v)
        g[v] = src[(size_t)(t + 16 * v) << 10];    // k1 = t+16v; 64B segments

    dft16<1, false>(g);                            // bins a = reg index
    {                                              // W256^{+t*a}: chain from W256^{+t}
        float2 wa = cexp_(PI2_256 * (float)t);
        float2 w = wa;
        g[1] = cmul(g[1], w);
#pragma unroll
        for (int r = 2; r < 16; ++r) { w = cmul(w, wa); g[r] = cmul(g[r], w); }
    }
#pragma unroll
    for (int r = 0; r < 16; ++r) lds[CIDX(r * 16 + t, c)] = g[r];
    __syncthreads();
#pragma unroll
    for (int u = 0; u < 16; ++u) g[u] = lds[CIDX(t * 16 + u, c)];

    dft16<1, false>(g);                            // n1 = t + 16b

    float* o0 = out + (size_t)(2 * z) * Lout;
    float* o1 = o0 + Lout;
#pragma unroll
    for (int r = 0; r < 16; ++r) {
        int n = ((t + 16 * r) << 10) + n2;
        if (n < Lout) { o0[n] = g[r].x; o1[n] = g[r].y; }
    }
}

extern "C" void kernel_launch(void* const* d_in, const int* in_sizes, int n_in,
                              void* d_out, int out_size, void* d_ws, size_t ws_size,
                              hipStream_t stream) {
    const float* audio = (const float*)d_in[0];   // (1, 4, T) f32
    const float* rir   = (const float*)d_in[1];   // (T,) f32
    float* out = (float*)d_out;                   // (1, 4, 2T-1) f32
    int Lout = out_size / 4;                      // 262143

    float2* A1  = (float2*)d_ws;                  // 3 * 2^18 complex (6.3 MB)
    float2* D   = A1 + 3 * NTOT;                  // 2 * 2^18 complex (4.2 MB)
    float2* tab = D + 2 * NTOT;                   // 1024 complex (8 KB)

    ka<<<192, 256, 0, stream>>>(audio, rir, A1, tab);
    kb<<<512, 256, 0, stream>>>(A1, D, tab);
    kc<<<256, 128, 0, stream>>>(D, out, Lout);
}

// Round 19
// 22.455 us; speedup vs baseline: 1.0938x; 1.0938x over previous
//
#include <hip/hip_runtime.h>

// FFT convolution via N = 2^18 = 256 x 1024 Cooley-Tukey, 3 dispatches
// (minimum for four-step: col-pass | row-local middle | col-pass).
// FINAL configuration = R14 structure (best measured: 22.6us).
//   n = 1024*n1 + n2 (nonzero n1<128), k = k1 + 256*k2.
// ka: 192 blocks x 256 (16 cols x 16 slots): distributed 256-pt column FFT
//     over n1 (+ W_N^{-n2 k1}) -> A1[seq][k1][n2].
// kb: 512 blocks x 256 (2 blocks/CU): fwd 1024-FFT rir row (regs) + fwd z row +
//     pointwise*1/N + inverse FFT + W_N^{+n2 k1} -> D[z][k1][n2].
// kc: 128 blocks x 256: distributed 256-pt inverse column FFT over k1, unpack.
// Probed and rejected: smaller column blocks (R15/R18: store/load granule loss >
// occupancy gain), paired-FFT barrier fusion (R17), extra dispatch splits (R13),
// all cross-block sync primitives (R6/R9/R10), transcendental reduction (R16: 0).

#define NTOT 262144
#define TLEN 131072
#define PI2_N    2.3968449808418217e-5f   /* 2*pi / 262144 */
#define PI2_1024 6.1359231515425649e-3f   /* 2*pi / 1024   */
#define PI2_256  2.4543692606170260e-2f   /* 2*pi / 256    */
#define LB(i) ((i) + ((i) >> 3))          /* LDS pad for row-FFT buffers */

__device__ __forceinline__ float2 cadd(float2 a, float2 b) { return make_float2(a.x + b.x, a.y + b.y); }
__device__ __forceinline__ float2 csub(float2 a, float2 b) { return make_float2(a.x - b.x, a.y - b.y); }
__device__ __forceinline__ float2 cmul(float2 a, float2 b) {
    return make_float2(a.x * b.x - a.y * b.y, a.x * b.y + a.y * b.x);
}
__device__ __forceinline__ float2 cmulc(float2 a, float2 b) {   // a * conj(b)
    return make_float2(a.x * b.x + a.y * b.y, a.y * b.x - a.x * b.y);
}
__device__ __forceinline__ float2 cexp_(float ang) {
    float s, c;
    __sincosf(ang, &s, &c);
    return make_float2(c, s);
}

// cos/sin(2*pi*k/16)
constexpr float CW16[16] = { 1.f, 0.92387953f, 0.70710678f, 0.38268343f, 0.f, -0.38268343f,
                             -0.70710678f, -0.92387953f, -1.f, -0.92387953f, -0.70710678f,
                             -0.38268343f, 0.f, 0.38268343f, 0.70710678f, 0.92387953f };
constexpr float SW16[16] = { 0.f, 0.38268343f, 0.70710678f, 0.92387953f, 1.f, 0.92387953f,
                             0.70710678f, 0.38268343f, 0.f, -0.38268343f, -0.70710678f,
                             -0.92387953f, -1.f, -0.92387953f, -0.70710678f, -0.38268343f };

template<int SIGN>
__device__ __forceinline__ void dft4(float2 x[4]) {
    float2 s0 = cadd(x[0], x[2]), d0 = csub(x[0], x[2]);
    float2 s1 = cadd(x[1], x[3]), d1 = csub(x[1], x[3]);
    float2 jd1 = (SIGN > 0) ? make_float2(-d1.y, d1.x) : make_float2(d1.y, -d1.x);
    x[0] = cadd(s0, s1);
    x[1] = cadd(d0, jd1);
    x[2] = csub(s0, s1);
    x[3] = csub(d0, jd1);
}

// Natural-order in-register 16-pt DFT (4x4). HZ: x[8..15] structurally zero (never read).
template<int SIGN, bool HZ>
__device__ __forceinline__ void dft16(float2 x[16]) {
    float2 A[4][4];                       // A[m0][j]
#pragma unroll
    for (int m0 = 0; m0 < 4; ++m0) {
        float2 g[4];
        if (HZ) {                         // dft4 of [a, b, 0, 0] over m1
            float2 a = x[m0], b = x[m0 + 4];
            float2 jb = (SIGN > 0) ? make_float2(-b.y, b.x) : make_float2(b.y, -b.x);
            g[0] = cadd(a, b);
            g[1] = cadd(a, jb);
            g[2] = csub(a, b);
            g[3] = csub(a, jb);
        } else {
            g[0] = x[m0]; g[1] = x[m0 + 4]; g[2] = x[m0 + 8]; g[3] = x[m0 + 12];
            dft4<SIGN>(g);
        }
#pragma unroll
        for (int j = 0; j < 4; ++j) {     // W16^{m0*j}, compile-time
            int k = (m0 * j) & 15;
            float2 w = make_float2(CW16[k], (SIGN < 0) ? -SW16[k] : SW16[k]);
            A[m0][j] = (m0 && j) ? cmul(g[j], w) : g[j];
        }
    }
#pragma unroll
    for (int j = 0; j < 4; ++j) {
        float2 g[4];
#pragma unroll
        for (int m0 = 0; m0 < 4; ++m0) g[m0] = A[m0][j];
        dft4<SIGN>(g);
#pragma unroll
        for (int l = 0; l < 4; ++l) x[j + 4 * l] = g[l];   // X[j+4l] natural
    }
}

template<int SIGN>
__device__ __forceinline__ void twtab4(float2 x[4], int base, const float2* __restrict__ tab) {
#pragma unroll
    for (int i = 1; i < 4; ++i) {
        float2 w = tab[base * i];          // base*i < 1024 at all call sites
        x[i] = (SIGN < 0) ? cmul(x[i], w) : cmulc(x[i], w);
    }
}

// 1024-pt radix-4 Stockham FFT, t in [0,256), x[i] = d[t+256i] natural in/out.
// 5 dft4 stages, 4 barriers, alternating L0/L1. Back-to-back calls WAR-safe.
template<int SIGN>
__device__ void fft1024(float2 x[4], int t, float2* L0, float2* L1,
                        const float2* __restrict__ tab) {
    dft4<SIGN>(x);
    twtab4<SIGN>(x, t, tab);
#pragma unroll
    for (int i = 0; i < 4; ++i) L0[LB(4 * t + i)] = x[i];
    __syncthreads();
    {
        int q = t & 3, p = t >> 2;
#pragma unroll
        for (int i = 0; i < 4; ++i) x[i] = L0[LB(q + 4 * p + 256 * i)];
        dft4<SIGN>(x);
        twtab4<SIGN>(x, 4 * p, tab);
#pragma unroll
        for (int i = 0; i < 4; ++i) L1[LB(q + 16 * p + 4 * i)] = x[i];
    }
    __syncthreads();
    {
        int q = t & 15, p = t >> 4;
#pragma unroll
        for (int i = 0; i < 4; ++i) x[i] = L1[LB(q + 16 * p + 256 * i)];
        dft4<SIGN>(x);
        twtab4<SIGN>(x, 16 * p, tab);
#pragma unroll
        for (int i = 0; i < 4; ++i) L0[LB(q + 64 * p + 16 * i)] = x[i];
    }
    __syncthreads();
    {
        int q = t & 63, p = t >> 6;
#pragma unroll
        for (int i = 0; i < 4; ++i) x[i] = L0[LB(q + 64 * p + 256 * i)];
        dft4<SIGN>(x);
        twtab4<SIGN>(x, 64 * p, tab);
#pragma unroll
        for (int i = 0; i < 4; ++i) L1[LB(q + 256 * p + 64 * i)] = x[i];
    }
    __syncthreads();
#pragma unroll
    for (int i = 0; i < 4; ++i) x[i] = L1[LB(t + 256 * i)];
    dft4<SIGN>(x);
}

// ka: 192 blocks x 256. 16 columns/block, 16 thr/column (c = tid&15 lane-consecutive).
__global__ void __launch_bounds__(256) ka(const float* __restrict__ audio,
                                          const float* __restrict__ rir,
                                          float2* __restrict__ A1,
                                          float2* __restrict__ tab) {
    __shared__ float2 lds[256 * 17];      // [a*16+u][c] padded row stride 17
    const int bid = blockIdx.x;
    const int tid = threadIdx.x;
    const int c = tid & 15;
    const int t = tid >> 4;               // 0..15

    if (bid < 4)                          // fill W1024 table for kb
        tab[bid * 256 + tid] = cexp_(-PI2_1024 * (float)(bid * 256 + tid));

    const int seq = bid >> 6;
    const int n2 = ((bid & 63) << 4) + c;

    float2 g[16];
    if (seq < 2) {
        const float* c0 = audio + (size_t)(2 * seq) * TLEN;
        const float* c1 = c0 + TLEN;
#pragma unroll
        for (int v = 0; v < 8; ++v) {     // n1 = t+16v < 128 nonzero half
            int n = ((t + 16 * v) << 10) + n2;
            g[v] = make_float2(c0[n], c1[n]);
        }
    } else {
#pragma unroll
        for (int v = 0; v < 8; ++v) {
            int n = ((t + 16 * v) << 10) + n2;
            g[v] = make_float2(rir[TLEN - 1 - n], 0.f);
        }
    }

    dft16<-1, true>(g);                   // bins a = reg index (natural)
    {                                     // W256^{-t*a}: chain from W256^{-t}
        float2 wa = cexp_(-PI2_256 * (float)t);
        float2 w = wa;
        g[1] = cmul(g[1], w);
#pragma unroll
        for (int r = 2; r < 16; ++r) { w = cmul(w, wa); g[r] = cmul(g[r], w); }
    }
#pragma unroll
    for (int r = 0; r < 16; ++r) lds[(r * 16 + t) * 17 + c] = g[r];
    __syncthreads();
#pragma unroll
    for (int u = 0; u < 16; ++u) g[u] = lds[(t * 16 + u) * 17 + c];  // a = t, sender u

    dft16<-1, false>(g);                  // over u -> bins b = reg index; k1 = t + 16b

    // W_N^{-n2*k1}, k1 = t+16r: base W_N^{-n2 t}, step W_N^{-16 n2}
    float2 w  = cexp_(-PI2_N * (float)(n2 * t));
    float2 ws = cexp_(-PI2_N * (float)(16 * n2));
    float2* dst = A1 + ((size_t)seq << 18) + n2;
#pragma unroll
    for (int r = 0; r < 16; ++r) {
        int k1 = t + 16 * r;
        dst[(size_t)k1 << 10] = cmul(g[r], w);
        w = cmul(w, ws);
    }
}

// kb: 512 blocks x 256. z = bid>>8, k1 = bid&255. Row-local middle (R14 exact):
// fwd FFT(rir row) -> 8 VGPRs; fwd FFT(z row); pointwise*1/N; inv FFT; twiddle -> D.
__global__ void __launch_bounds__(256) kb(const float2* __restrict__ A1,
                                          float2* __restrict__ D,
                                          const float2* __restrict__ tab) {
    __shared__ float2 L0[1152], L1[1152];
    const int t = threadIdx.x;
    const int k1 = blockIdx.x & 255;

    const float2* sz = A1 + ((size_t)blockIdx.x << 10);          // z row = z*256+k1 = bid
    const float2* sr = A1 + ((size_t)(512 + k1) << 10);          // rir row
    float2 x[4], r4[4];
#pragma unroll
    for (int i = 0; i < 4; ++i) x[i] = sz[t + 256 * i];          // issue early: both
#pragma unroll
    for (int i = 0; i < 4; ++i) r4[i] = sr[t + 256 * i];         // rows in flight

    fft1024<-1>(r4, t, L0, L1, tab);     // rir spectrum (z loads hide under this)
    fft1024<-1>(x, t, L0, L1, tab);      // z spectrum

    const float invN = 3.814697265625e-6f;   // 1/262144
#pragma unroll
    for (int i = 0; i < 4; ++i) {
        float2 y = cmul(x[i], r4[i]);
        x[i] = make_float2(y.x * invN, y.y * invN);
    }

    fft1024<1>(x, t, L0, L1, tab);

    // W_N^{+n2 k1}, n2 = t+256i: w = e^{+i th(t k1)}, step = conj(tab[k1])
    float2 w  = cexp_(PI2_N * (float)(t * k1));
    float2 st = make_float2(tab[k1].x, -tab[k1].y);
    float2* d = D + ((size_t)blockIdx.x << 10) + t;
#pragma unroll
    for (int i = 0; i < 4; ++i) {
        d[256 * i] = cmul(x[i], w);
        w = cmul(w, st);
    }
}

// kc: 128 blocks x 256. Distributed 256-pt inverse column FFT over k1 + unpack.
__global__ void __launch_bounds__(256) kc(const float2* __restrict__ D,
                                          float* __restrict__ out, int Lout) {
    __shared__ float2 lds[256 * 17];
    const int bid = blockIdx.x;
    const int tid = threadIdx.x;
    const int c = tid & 15;
    const int t = tid >> 4;
    const int z = bid >> 6;
    const int n2 = ((bid & 63) << 4) + c;

    const float2* src = D + ((size_t)z << 18) + n2;
    float2 g[16];
#pragma unroll
    for (int v = 0; v < 16; ++v)
        g[v] = src[(size_t)(t + 16 * v) << 10];    // k1 = t+16v; 128B coalesced chunks

    dft16<1, false>(g);                            // bins a = reg index
    {                                              // W256^{+t*a}: chain from W256^{+t}
        float2 wa = cexp_(PI2_256 * (float)t);
        float2 w = wa;
        g[1] = cmul(g[1], w);
#pragma unroll
        for (int r = 2; r < 16; ++r) { w = cmul(w, wa); g[r] = cmul(g[r], w); }
    }
#pragma unroll
    for (int r = 0; r < 16; ++r) lds[(r * 16 + t) * 17 + c] = g[r];
    __syncthreads();
#pragma unroll
    for (int u = 0; u < 16; ++u) g[u] = lds[(t * 16 + u) * 17 + c];

    dft16<1, false>(g);                            // n1 = t + 16b

    float* o0 = out + (size_t)(2 * z) * Lout;
    float* o1 = o0 + Lout;
#pragma unroll
    for (int r = 0; r < 16; ++r) {
        int n = ((t + 16 * r) << 10) + n2;
        if (n < Lout) { o0[n] = g[r].x; o1[n] = g[r].y; }
    }
}

extern "C" void kernel_launch(void* const* d_in, const int* in_sizes, int n_in,
                              void* d_out, int out_size, void* d_ws, size_t ws_size,
                              hipStream_t stream) {
    const float* audio = (const float*)d_in[0];   // (1, 4, T) f32
    const float* rir   = (const float*)d_in[1];   // (T,) f32
    float* out = (float*)d_out;                   // (1, 4, 2T-1) f32
    int Lout = out_size / 4;                      // 262143

    float2* A1  = (float2*)d_ws;                  // 3 * 2^18 complex (6.3 MB)
    float2* D   = A1 + 3 * NTOT;                  // 2 * 2^18 complex (4.2 MB)
    float2* tab = D + 2 * NTOT;                   // 1024 complex (8 KB)

    ka<<<192, 256, 0, stream>>>(audio, rir, A1, tab);
    kb<<<512, 256, 0, stream>>>(A1, D, tab);
    kc<<<128, 256, 0, stream>>>(D, out, Lout);
}